// Round 6
// baseline (338.588 us; speedup 1.0000x reference)
//
#include <hip/hip_runtime.h>
#include <hip/hip_bf16.h>
#include <math.h>

#define B_ 32
#define L_ 720
#define N_ 512
#define H_ 16
#define D_ 64
#define TOPK_ 8
#define M_ (B_ * L_)          // 23040 rows
#define RPB 8                 // rows per ring block
#define CRCH 16               // center_raw chunks per batch
#define CRL (L_ / CRCH)       // 45
#define MT 64                 // rows per mega block (23040/64 = 360 blocks)

typedef __bf16 bf16x8 __attribute__((ext_vector_type(8)));
typedef float f32x16 __attribute__((ext_vector_type(16)));

// ---------------------------------------------------------------------------
// async 16B global -> LDS (dest = wave-uniform lds base + lane*16)
// ---------------------------------------------------------------------------
__device__ __forceinline__ void async_cp16(const __hip_bfloat16* g, __hip_bfloat16* l) {
    __builtin_amdgcn_global_load_lds(
        (const __attribute__((address_space(1))) void*)g,
        (__attribute__((address_space(3))) void*)l, 16, 0, 0);
}

// swizzled element index inside a 512-wide bf16 LDS tile (16B-chunk XOR by row)
__device__ __forceinline__ int sw_idx(int row, int col) {
    return row * 512 + (((col >> 3) ^ (row & 7)) << 3) + (col & 7);
}

// ---------------------------------------------------------------------------
// Kernel 1: prep = weight transpose/convert (blocks 0..1023) + Q/K proj
// (blocks 1024..1055). 256 threads.
// ---------------------------------------------------------------------------
__global__ __launch_bounds__(256) void prep_kernel(
    const float* __restrict__ Wg, const float* __restrict__ Wf,
    __hip_bfloat16* __restrict__ WgT, __hip_bfloat16* __restrict__ WfT,
    const float* __restrict__ ve,
    const float* __restrict__ Wq, const float* __restrict__ bq,
    const float* __restrict__ Wk, const float* __restrict__ bk,
    float* __restrict__ Qm, float* __restrict__ Km)
{
    if (blockIdx.x < 1024) {
        const int n = blockIdx.x & 511;
        const bool isf = blockIdx.x >= 512;
        const float* src = isf ? Wf : Wg;
        __hip_bfloat16* dst = isf ? WfT : WgT;
        for (int k = threadIdx.x; k < N_; k += 256)
            dst[n * N_ + k] = __float2bfloat16(src[(size_t)k * N_ + n]);
    } else {
        const int g = (blockIdx.x - 1024) * 256 + threadIdx.x;  // 0..8191
        const int j = g >> 4, h = g & 15;
        const float* vr = ve + j * H_;
        float q = bq[h], k = bk[h];
        #pragma unroll
        for (int m = 0; m < H_; ++m) {
            const float v = vr[m];
            q += v * Wq[m * H_ + h];
            k += v * Wk[m * H_ + h];
        }
        Qm[g] = q;
        Km[g] = k;
    }
}

// ---------------------------------------------------------------------------
// Kernel 2: top-8 neighbors. One wave per row n; shuffle-only selection.
// ---------------------------------------------------------------------------
__global__ __launch_bounds__(64) void topk_kernel(
    const float* __restrict__ Qm, const float* __restrict__ Km,
    float* __restrict__ w_out, int* __restrict__ idx_out)
{
    const int n = blockIdx.x;
    const int lane = threadIdx.x;

    float4 q0, q1, q2, q3;
    {
        const float4* qr = (const float4*)(Qm + n * H_);
        q0 = qr[0]; q1 = qr[1]; q2 = qr[2]; q3 = qr[3];
    }

    float sv[8]; int si[8];
    #pragma unroll
    for (int c = 0; c < 8; ++c) {
        const int j = c * 64 + lane;
        const float4* kr = (const float4*)(Km + j * H_);
        float4 k0 = kr[0], k1 = kr[1], k2 = kr[2], k3 = kr[3];
        float s = q0.x * k0.x + q0.y * k0.y + q0.z * k0.z + q0.w * k0.w
                + q1.x * k1.x + q1.y * k1.y + q1.z * k1.z + q1.w * k1.w
                + q2.x * k2.x + q2.y * k2.y + q2.z * k2.z + q2.w * k2.w
                + q3.x * k3.x + q3.y * k3.y + q3.z * k3.z + q3.w * k3.w;
        sv[c] = (j == n) ? -1e9f : s;
        si[c] = j;
    }

    float keepv[TOPK_]; int keepi[TOPK_];
    #pragma unroll
    for (int k = 0; k < TOPK_; ++k) {
        float bv = sv[0]; int bi = si[0]; int bslot = 0;
        #pragma unroll
        for (int c = 1; c < 8; ++c)
            if (sv[c] > bv || (sv[c] == bv && si[c] < bi)) { bv = sv[c]; bi = si[c]; bslot = c; }
        float v = bv; int i = bi;
        #pragma unroll
        for (int off = 32; off > 0; off >>= 1) {
            float v2 = __shfl_xor(v, off);
            int   i2 = __shfl_xor(i, off);
            if (v2 > v || (v2 == v && i2 < i)) { v = v2; i = i2; }
        }
        keepv[k] = v; keepi[k] = i;
        if (i == bi) sv[bslot] = -INFINITY;
    }

    if (lane == 0) {
        float vmax = keepv[0];
        float ev[TOPK_], esum = 0.f;
        #pragma unroll
        for (int k = 0; k < TOPK_; k++) { ev[k] = expf(keepv[k] - vmax); esum += ev[k]; }
        float inv = 1.f / esum;
        #pragma unroll
        for (int k = 0; k < TOPK_; k++) {
            w_out[n * TOPK_ + k] = ev[k] * inv;
            idx_out[n * TOPK_ + k] = keepi[k];
        }
    }
}

// ---------------------------------------------------------------------------
// Kernel 3: ring gather -> bf16 A matrix, fused with score s = x·Wscore+b.
// ---------------------------------------------------------------------------
__global__ __launch_bounds__(512) void ring_kernel(
    const float* __restrict__ x, const float* __restrict__ w,
    const int* __restrict__ idx,
    const float* __restrict__ Wscore, const float* __restrict__ bscore,
    __hip_bfloat16* __restrict__ ring, float* __restrict__ s)
{
    __shared__ float xs[RPB][N_];
    __shared__ float wsh[N_ * TOPK_];
    __shared__ int   ish[N_ * TOPK_];
    const int t = threadIdx.x;
    const int row0 = blockIdx.x * RPB;

    for (int i = t; i < N_ * TOPK_; i += 512) { wsh[i] = w[i]; ish[i] = idx[i]; }
    {
        const float4* xg = (const float4*)(x + (size_t)row0 * N_);
        float4* xsf = (float4*)&xs[0][0];
        xsf[t] = xg[t];
        xsf[t + 512] = xg[t + 512];
    }
    __syncthreads();

    {
        const int wv = t >> 6, lane = t & 63;
        float sa = 0.f;
        #pragma unroll
        for (int i = 0; i < 8; ++i) sa += xs[wv][lane + i * 64] * Wscore[lane + i * 64];
        for (int off = 32; off > 0; off >>= 1) sa += __shfl_down(sa, off);
        if (lane == 0) s[row0 + wv] = sa + bscore[0];
    }

    float wr[TOPK_]; int ir[TOPK_];
    #pragma unroll
    for (int k = 0; k < TOPK_; ++k) { wr[k] = wsh[t * TOPK_ + k]; ir[k] = ish[t * TOPK_ + k]; }
    #pragma unroll
    for (int r = 0; r < RPB; ++r) {
        float acc = 0.f;
        #pragma unroll
        for (int k = 0; k < TOPK_; ++k) acc += wr[k] * xs[r][ir[k]];
        ring[(size_t)(row0 + r) * N_ + t] = __float2bfloat16(acc);
    }
}

// ---------------------------------------------------------------------------
// Kernel 4: partial center_raw with INLINE softmax (raw s in, no separate
// softmax kernel). grid B_*CRCH, 512 threads.
// ---------------------------------------------------------------------------
__global__ __launch_bounds__(512) void center_raw_kernel(
    const float* __restrict__ x, const float* __restrict__ s,
    float* __restrict__ craw_p)
{
    const int b = blockIdx.x >> 4;
    const int c = blockIdx.x & 15;
    const int n = threadIdx.x;
    __shared__ float red[8];
    __shared__ float ash[CRL];
    const float* srow = s + (size_t)b * L_;

    const float v1 = srow[n];
    const float v2 = (n < L_ - 512) ? srow[512 + n] : -1e30f;
    float lmax = fmaxf(v1, v2);
    for (int off = 32; off > 0; off >>= 1) lmax = fmaxf(lmax, __shfl_xor(lmax, off));
    if ((n & 63) == 0) red[n >> 6] = lmax;
    __syncthreads();
    float gmax = red[0];
    #pragma unroll
    for (int i = 1; i < 8; ++i) gmax = fmaxf(gmax, red[i]);
    __syncthreads();
    float lsum = expf(v1 - gmax) + ((n < L_ - 512) ? expf(v2 - gmax) : 0.f);
    for (int off = 32; off > 0; off >>= 1) lsum += __shfl_xor(lsum, off);
    if ((n & 63) == 0) red[n >> 6] = lsum;
    __syncthreads();
    float gsum = 0.f;
    #pragma unroll
    for (int i = 0; i < 8; ++i) gsum += red[i];
    const float inv = 1.f / gsum;

    const int l0 = c * CRL;
    if (n < CRL) ash[n] = expf(srow[l0 + n] - gmax) * inv;
    __syncthreads();

    const float* xb = x + ((size_t)b * L_ + l0) * N_;
    float acc = 0.f;
    #pragma unroll 3
    for (int l = 0; l < CRL; l++) acc += ash[l] * xb[(size_t)l * N_ + n];
    craw_p[(size_t)(b * CRCH + c) * N_ + n] = acc;
}

__device__ __forceinline__ float gelu_exact(float v) {
    return 0.5f * v * (1.0f + erff(v * 0.70710678118654752440f));
}

// ---------------------------------------------------------------------------
// Kernel 5: reduce partials + center MLP -> center. grid B_, 512 thr.
// ---------------------------------------------------------------------------
__global__ __launch_bounds__(512) void center_mlp_kernel(
    const float* __restrict__ craw_p,
    const float* __restrict__ Wc1, const float* __restrict__ bc1,
    const float* __restrict__ Wc2, const float* __restrict__ bc2,
    const float* __restrict__ Wcn, const float* __restrict__ bcn,
    float* __restrict__ center)
{
    const int b = blockIdx.x;
    const int t = threadIdx.x;
    const int col = t & 63;
    const int seg = t >> 6;
    __shared__ float cr[N_];
    __shared__ float psum[8][D_];
    __shared__ float h1[D_];
    __shared__ float h2[D_];

    {
        float acc = 0.f;
        #pragma unroll
        for (int c = 0; c < CRCH; ++c) acc += craw_p[(size_t)(b * CRCH + c) * N_ + t];
        cr[t] = acc;
    }
    __syncthreads();
    {
        float p = 0.f;
        #pragma unroll 8
        for (int m = seg * 64; m < seg * 64 + 64; ++m) p += cr[m] * Wc1[m * D_ + col];
        psum[seg][col] = p;
    }
    __syncthreads();
    if (t < D_) {
        float acc = bc1[t];
        #pragma unroll
        for (int s2 = 0; s2 < 8; ++s2) acc += psum[s2][t];
        h1[t] = gelu_exact(acc);
    }
    __syncthreads();
    if (t < D_) {
        float acc = bc2[t];
        #pragma unroll 8
        for (int j = 0; j < D_; j++) acc += h1[j] * Wc2[j * D_ + t];
        h2[t] = gelu_exact(acc);
    }
    __syncthreads();
    {
        float acc = bcn[t];
        #pragma unroll 8
        for (int j = 0; j < D_; j++) acc += h2[j] * Wcn[j * N_ + t];
        center[b * N_ + t] = acc;
    }
}

// ---------------------------------------------------------------------------
// Kernel 6: cg[b,n] = center[b]·Wg[512+.,n] + bg[n].
// ---------------------------------------------------------------------------
__global__ __launch_bounds__(512) void cg_kernel(
    const float* __restrict__ center, const float* __restrict__ Wg,
    const float* __restrict__ bg, float* __restrict__ cg)
{
    const int nc = blockIdx.x;
    const int b  = blockIdx.y;
    const int t  = threadIdx.x;
    const int col = nc * 64 + (t & 63);
    const int seg = t >> 6;
    __shared__ float cs[N_];
    __shared__ float psum[8][64];

    cs[t] = center[b * N_ + t];
    __syncthreads();
    {
        float p = 0.f;
        const float* wp = Wg + (size_t)(N_ + seg * 64) * N_ + col;
        #pragma unroll 8
        for (int m = 0; m < 64; ++m) { p += cs[seg * 64 + m] * wp[0]; wp += N_; }
        psum[seg][t & 63] = p;
    }
    __syncthreads();
    if (t < 64) {
        float acc = bg[nc * 64 + t];
        #pragma unroll
        for (int s2 = 0; s2 < 8; ++s2) acc += psum[s2][t];
        cg[b * N_ + nc * 64 + t] = acc;
    }
}

// ---------------------------------------------------------------------------
// Kernel 7 (MEGA): gate GEMM + fuse + out GEMM + residual + LayerNorm,
// one 64-row x 512-col tile per block. 512 threads = 8 waves.
// Wave (wr = wv>>2, wc = wv&3): rows wr*32..+31, cols wc*128..+127 (ni 0..3).
// A tile (ring 64x512 bf16, swizzled) staged once in 64 KB LDS; B fragments
// streamed from L2-resident WgT/WfT; gate epilogue rewrites A in place
// (ring -> fused); LN scratch reuses dead A-tile LDS.
// ---------------------------------------------------------------------------
#define KLOOP(ATILE, BPTR, ACC)                                                \
    _Pragma("unroll 4")                                                        \
    for (int ks = 0; ks < 32; ++ks) {                                          \
        const int arow = wr * 32 + m32;                                        \
        bf16x8 a = *(const bf16x8*)(ATILE + arow * 512 +                       \
                      (((2 * ks + half) ^ (arow & 7)) << 3));                  \
        _Pragma("unroll")                                                      \
        for (int ni = 0; ni < 4; ++ni) {                                       \
            const int n = wc * 128 + ni * 32 + m32;                            \
            bf16x8 b = *(const bf16x8*)(BPTR + (size_t)n * 512 +               \
                                        ks * 16 + half * 8);                   \
            ACC[ni] = __builtin_amdgcn_mfma_f32_32x32x16_bf16(a, b, ACC[ni], 0, 0, 0); \
        }                                                                      \
    }

__global__ __launch_bounds__(512, 2) void mega_kernel(
    const __hip_bfloat16* __restrict__ ring,
    const __hip_bfloat16* __restrict__ WgT,
    const __hip_bfloat16* __restrict__ WfT,
    const float* __restrict__ cg, const float* __restrict__ center,
    const float* __restrict__ x, const float* __restrict__ bfv,
    const float* __restrict__ gamma, const float* __restrict__ beta,
    float* __restrict__ out)
{
    __shared__ __hip_bfloat16 Ash[MT * 512];        // 64 KB; later reused as LN scratch
    const int tid  = threadIdx.x;
    const int lane = tid & 63;
    const int wv   = tid >> 6;
    const int m32  = lane & 31;
    const int half = lane >> 5;
    const int wr   = wv >> 2;      // 0..1
    const int wc   = wv & 3;       // 0..3
    const int row0 = blockIdx.x * MT;

    // stage ring rows: wave wv stages rows wv*8..wv*8+7, one row (1 KB) per instr
    #pragma unroll
    for (int r8 = 0; r8 < 8; ++r8) {
        const int r = wv * 8 + r8;
        async_cp16(ring + (size_t)(row0 + r) * N_ + ((lane ^ (r & 7)) << 3),
                   Ash + r * 512);
    }
    __syncthreads();

    f32x16 acc[4];
    #pragma unroll
    for (int ni = 0; ni < 4; ++ni)
        #pragma unroll
        for (int e = 0; e < 16; ++e) acc[ni][e] = 0.f;

    // ---- gate GEMM: ring @ WgT^T ----
    KLOOP(Ash, WgT, acc)
    __syncthreads();   // all a-frag reads done before in-place rewrite

    // ---- gate epilogue: fused = g*ring + (1-g)*center, in place in Ash ----
    #pragma unroll
    for (int ni = 0; ni < 4; ++ni) {
        const int col = wc * 128 + ni * 32 + m32;
        #pragma unroll
        for (int reg = 0; reg < 16; ++reg) {
            const int rl = wr * 32 + (reg & 3) + 8 * (reg >> 2) + 4 * half;
            const int rg = row0 + rl;
            const int b  = rg / L_;
            const float logit = acc[ni][reg] + cg[b * N_ + col];
            const float g = 1.f / (1.f + expf(-logit));
            const int ix = sw_idx(rl, col);
            const float rv = __bfloat162float(Ash[ix]);
            const float f = g * rv + (1.f - g) * center[b * N_ + col];
            Ash[ix] = __float2bfloat16(f);
        }
    }
    __syncthreads();

    #pragma unroll
    for (int ni = 0; ni < 4; ++ni)
        #pragma unroll
        for (int e = 0; e < 16; ++e) acc[ni][e] = 0.f;

    // ---- out GEMM: fused @ WfT^T ----
    KLOOP(Ash, WfT, acc)

    // ---- h = acc + bf + x ----
    #pragma unroll
    for (int ni = 0; ni < 4; ++ni) {
        const int col = wc * 128 + ni * 32 + m32;
        const float bfc = bfv[col];
        #pragma unroll
        for (int reg = 0; reg < 16; ++reg) {
            const int rl = wr * 32 + (reg & 3) + 8 * (reg >> 2) + 4 * half;
            acc[ni][reg] += bfc + x[(size_t)(row0 + rl) * N_ + col];
        }
    }
    __syncthreads();   // Ash (fused) now dead -> reuse as LN scratch

    float* rsum = (float*)Ash;          // [4][64]
    float* rsq  = (float*)Ash + 256;    // [4][64]
    float* muv  = (float*)Ash + 512;    // [64][2]

    // ---- per-row partial sums over this wave's 128 cols ----
    #pragma unroll
    for (int reg = 0; reg < 16; ++reg) {
        float sv = acc[0][reg] + acc[1][reg] + acc[2][reg] + acc[3][reg];
        float qv = acc[0][reg] * acc[0][reg] + acc[1][reg] * acc[1][reg]
                 + acc[2][reg] * acc[2][reg] + acc[3][reg] * acc[3][reg];
        #pragma unroll
        for (int off = 16; off > 0; off >>= 1) {
            sv += __shfl_xor(sv, off);
            qv += __shfl_xor(qv, off);
        }
        if (m32 == 0) {
            const int rl = wr * 32 + (reg & 3) + 8 * (reg >> 2) + 4 * half;
            rsum[wc * 64 + rl] = sv;
            rsq [wc * 64 + rl] = qv;
        }
    }
    __syncthreads();
    if (tid < 64) {
        const float S = rsum[tid] + rsum[64 + tid] + rsum[128 + tid] + rsum[192 + tid];
        const float Q = rsq[tid]  + rsq[64 + tid]  + rsq[128 + tid]  + rsq[192 + tid];
        const float mu  = S * (1.0f / N_);
        const float var = Q * (1.0f / N_) - mu * mu;
        muv[tid * 2]     = mu;
        muv[tid * 2 + 1] = 1.0f / sqrtf(var + 1e-5f);
    }
    __syncthreads();

    // ---- normalize + store ----
    #pragma unroll
    for (int ni = 0; ni < 4; ++ni) {
        const int col = wc * 128 + ni * 32 + m32;
        const float gm = gamma[col];
        const float bt = beta[col];
        #pragma unroll
        for (int reg = 0; reg < 16; ++reg) {
            const int rl = wr * 32 + (reg & 3) + 8 * (reg >> 2) + 4 * half;
            out[(size_t)(row0 + rl) * N_ + col] =
                (acc[ni][reg] - muv[rl * 2]) * muv[rl * 2 + 1] * gm + bt;
        }
    }
}

// ---------------------------------------------------------------------------
extern "C" void kernel_launch(void* const* d_in, const int* in_sizes, int n_in,
                              void* d_out, int out_size, void* d_ws, size_t ws_size,
                              hipStream_t stream) {
    const float* x       = (const float*)d_in[0];
    const float* ve      = (const float*)d_in[1];
    const float* Wq      = (const float*)d_in[2];
    const float* bq      = (const float*)d_in[3];
    const float* Wk      = (const float*)d_in[4];
    const float* bk      = (const float*)d_in[5];
    const float* Wscore  = (const float*)d_in[6];
    const float* bscore  = (const float*)d_in[7];
    const float* Wc1     = (const float*)d_in[8];
    const float* bc1     = (const float*)d_in[9];
    const float* Wc2     = (const float*)d_in[10];
    const float* bc2     = (const float*)d_in[11];
    const float* Wcn     = (const float*)d_in[12];
    const float* bcn     = (const float*)d_in[13];
    const float* Wg      = (const float*)d_in[14];
    const float* bg      = (const float*)d_in[15];
    const float* Wf      = (const float*)d_in[16];
    const float* bf      = (const float*)d_in[17];
    const float* gamma   = (const float*)d_in[18];
    const float* beta    = (const float*)d_in[19];
    float* out = (float*)d_out;

    char* p = (char*)d_ws;
    float* ws_w    = (float*)p; p += N_ * TOPK_ * sizeof(float);
    int*   ws_idx  = (int*)p;   p += N_ * TOPK_ * sizeof(int);
    float* ws_s    = (float*)p; p += B_ * L_ * sizeof(float);
    float* ws_crp  = (float*)p; p += B_ * CRCH * N_ * sizeof(float);
    float* ws_cent = (float*)p; p += B_ * N_ * sizeof(float);
    float* ws_cg   = (float*)p; p += B_ * N_ * sizeof(float);
    float* ws_Q    = (float*)p; p += N_ * H_ * sizeof(float);
    float* ws_K    = (float*)p; p += N_ * H_ * sizeof(float);
    __hip_bfloat16* ws_ring = (__hip_bfloat16*)p; p += (size_t)M_ * N_ * sizeof(__hip_bfloat16);
    __hip_bfloat16* ws_WgT  = (__hip_bfloat16*)p; p += (size_t)N_ * N_ * sizeof(__hip_bfloat16);
    __hip_bfloat16* ws_WfT  = (__hip_bfloat16*)p; p += (size_t)N_ * N_ * sizeof(__hip_bfloat16);

    prep_kernel<<<1056, 256, 0, stream>>>(Wg, Wf, ws_WgT, ws_WfT,
                                          ve, Wq, bq, Wk, bk, ws_Q, ws_K);
    topk_kernel<<<N_, 64, 0, stream>>>(ws_Q, ws_K, ws_w, ws_idx);
    ring_kernel<<<M_ / RPB, 512, 0, stream>>>(x, ws_w, ws_idx, Wscore, bscore,
                                              ws_ring, ws_s);
    center_raw_kernel<<<B_ * CRCH, 512, 0, stream>>>(x, ws_s, ws_crp);
    center_mlp_kernel<<<B_, 512, 0, stream>>>(ws_crp, Wc1, bc1, Wc2, bc2,
                                              Wcn, bcn, ws_cent);
    cg_kernel<<<dim3(8, B_), 512, 0, stream>>>(ws_cent, Wg, bg, ws_cg);
    mega_kernel<<<M_ / MT, 512, 0, stream>>>(ws_ring, ws_WgT, ws_WfT,
                                             ws_cg, ws_cent, x, bf,
                                             gamma, beta, out);
}

// Round 7
// 310.637 us; speedup vs baseline: 1.0900x; 1.0900x over previous
//
#include <hip/hip_runtime.h>
#include <hip/hip_bf16.h>
#include <math.h>

#define B_ 32
#define L_ 720
#define N_ 512
#define H_ 16
#define D_ 64
#define TOPK_ 8
#define M_ (B_ * L_)          // 23040 rows
#define RPB 8                 // rows per ring block
#define CRCH 16               // center_raw chunks per batch
#define CRL (L_ / CRCH)       // 45
#define MT 64                 // rows per mega block (23040/64 = 360 blocks)

typedef __bf16 bf16x8 __attribute__((ext_vector_type(8)));
typedef float f32x16 __attribute__((ext_vector_type(16)));

// ---------------------------------------------------------------------------
// async 16B global -> LDS (dest = wave-uniform lds base + lane*16)
// ---------------------------------------------------------------------------
__device__ __forceinline__ void async_cp16(const __hip_bfloat16* g, __hip_bfloat16* l) {
    __builtin_amdgcn_global_load_lds(
        (const __attribute__((address_space(1))) void*)g,
        (__attribute__((address_space(3))) void*)l, 16, 0, 0);
}

// swizzled element index inside a 512-wide bf16 LDS tile (16B-chunk XOR by row)
__device__ __forceinline__ int sw_idx(int row, int col) {
    return row * 512 + (((col >> 3) ^ (row & 7)) << 3) + (col & 7);
}

// ---------------------------------------------------------------------------
// Kernel 1: prep = weight transpose/convert (blocks 0..1023) + Q/K proj
// (blocks 1024..1055). 256 threads.
// ---------------------------------------------------------------------------
__global__ __launch_bounds__(256) void prep_kernel(
    const float* __restrict__ Wg, const float* __restrict__ Wf,
    __hip_bfloat16* __restrict__ WgT, __hip_bfloat16* __restrict__ WfT,
    const float* __restrict__ ve,
    const float* __restrict__ Wq, const float* __restrict__ bq,
    const float* __restrict__ Wk, const float* __restrict__ bk,
    float* __restrict__ Qm, float* __restrict__ Km)
{
    if (blockIdx.x < 1024) {
        const int n = blockIdx.x & 511;
        const bool isf = blockIdx.x >= 512;
        const float* src = isf ? Wf : Wg;
        __hip_bfloat16* dst = isf ? WfT : WgT;
        for (int k = threadIdx.x; k < N_; k += 256)
            dst[n * N_ + k] = __float2bfloat16(src[(size_t)k * N_ + n]);
    } else {
        const int g = (blockIdx.x - 1024) * 256 + threadIdx.x;  // 0..8191
        const int j = g >> 4, h = g & 15;
        const float* vr = ve + j * H_;
        float q = bq[h], k = bk[h];
        #pragma unroll
        for (int m = 0; m < H_; ++m) {
            const float v = vr[m];
            q += v * Wq[m * H_ + h];
            k += v * Wk[m * H_ + h];
        }
        Qm[g] = q;
        Km[g] = k;
    }
}

// ---------------------------------------------------------------------------
// Kernel 2: top-8 neighbors. One wave per row n; shuffle-only selection.
// ---------------------------------------------------------------------------
__global__ __launch_bounds__(64) void topk_kernel(
    const float* __restrict__ Qm, const float* __restrict__ Km,
    float* __restrict__ w_out, int* __restrict__ idx_out)
{
    const int n = blockIdx.x;
    const int lane = threadIdx.x;

    float4 q0, q1, q2, q3;
    {
        const float4* qr = (const float4*)(Qm + n * H_);
        q0 = qr[0]; q1 = qr[1]; q2 = qr[2]; q3 = qr[3];
    }

    float sv[8]; int si[8];
    #pragma unroll
    for (int c = 0; c < 8; ++c) {
        const int j = c * 64 + lane;
        const float4* kr = (const float4*)(Km + j * H_);
        float4 k0 = kr[0], k1 = kr[1], k2 = kr[2], k3 = kr[3];
        float s = q0.x * k0.x + q0.y * k0.y + q0.z * k0.z + q0.w * k0.w
                + q1.x * k1.x + q1.y * k1.y + q1.z * k1.z + q1.w * k1.w
                + q2.x * k2.x + q2.y * k2.y + q2.z * k2.z + q2.w * k2.w
                + q3.x * k3.x + q3.y * k3.y + q3.z * k3.z + q3.w * k3.w;
        sv[c] = (j == n) ? -1e9f : s;
        si[c] = j;
    }

    float keepv[TOPK_]; int keepi[TOPK_];
    #pragma unroll
    for (int k = 0; k < TOPK_; ++k) {
        float bv = sv[0]; int bi = si[0]; int bslot = 0;
        #pragma unroll
        for (int c = 1; c < 8; ++c)
            if (sv[c] > bv || (sv[c] == bv && si[c] < bi)) { bv = sv[c]; bi = si[c]; bslot = c; }
        float v = bv; int i = bi;
        #pragma unroll
        for (int off = 32; off > 0; off >>= 1) {
            float v2 = __shfl_xor(v, off);
            int   i2 = __shfl_xor(i, off);
            if (v2 > v || (v2 == v && i2 < i)) { v = v2; i = i2; }
        }
        keepv[k] = v; keepi[k] = i;
        if (i == bi) sv[bslot] = -INFINITY;
    }

    if (lane == 0) {
        float vmax = keepv[0];
        float ev[TOPK_], esum = 0.f;
        #pragma unroll
        for (int k = 0; k < TOPK_; k++) { ev[k] = expf(keepv[k] - vmax); esum += ev[k]; }
        float inv = 1.f / esum;
        #pragma unroll
        for (int k = 0; k < TOPK_; k++) {
            w_out[n * TOPK_ + k] = ev[k] * inv;
            idx_out[n * TOPK_ + k] = keepi[k];
        }
    }
}

// ---------------------------------------------------------------------------
// Kernel 3: ring gather -> bf16 A matrix, fused with score s = x·Wscore+b.
// ---------------------------------------------------------------------------
__global__ __launch_bounds__(512) void ring_kernel(
    const float* __restrict__ x, const float* __restrict__ w,
    const int* __restrict__ idx,
    const float* __restrict__ Wscore, const float* __restrict__ bscore,
    __hip_bfloat16* __restrict__ ring, float* __restrict__ s)
{
    __shared__ float xs[RPB][N_];
    __shared__ float wsh[N_ * TOPK_];
    __shared__ int   ish[N_ * TOPK_];
    const int t = threadIdx.x;
    const int row0 = blockIdx.x * RPB;

    for (int i = t; i < N_ * TOPK_; i += 512) { wsh[i] = w[i]; ish[i] = idx[i]; }
    {
        const float4* xg = (const float4*)(x + (size_t)row0 * N_);
        float4* xsf = (float4*)&xs[0][0];
        xsf[t] = xg[t];
        xsf[t + 512] = xg[t + 512];
    }
    __syncthreads();

    {
        const int wv = t >> 6, lane = t & 63;
        float sa = 0.f;
        #pragma unroll
        for (int i = 0; i < 8; ++i) sa += xs[wv][lane + i * 64] * Wscore[lane + i * 64];
        for (int off = 32; off > 0; off >>= 1) sa += __shfl_down(sa, off);
        if (lane == 0) s[row0 + wv] = sa + bscore[0];
    }

    float wr[TOPK_]; int ir[TOPK_];
    #pragma unroll
    for (int k = 0; k < TOPK_; ++k) { wr[k] = wsh[t * TOPK_ + k]; ir[k] = ish[t * TOPK_ + k]; }
    #pragma unroll
    for (int r = 0; r < RPB; ++r) {
        float acc = 0.f;
        #pragma unroll
        for (int k = 0; k < TOPK_; ++k) acc += wr[k] * xs[r][ir[k]];
        ring[(size_t)(row0 + r) * N_ + t] = __float2bfloat16(acc);
    }
}

// ---------------------------------------------------------------------------
// Kernel 4: partial center_raw with inline softmax. grid B_*CRCH, 512 thr.
// ---------------------------------------------------------------------------
__global__ __launch_bounds__(512) void center_raw_kernel(
    const float* __restrict__ x, const float* __restrict__ s,
    float* __restrict__ craw_p)
{
    const int b = blockIdx.x >> 4;
    const int c = blockIdx.x & 15;
    const int n = threadIdx.x;
    __shared__ float red[8];
    __shared__ float ash[CRL];
    const float* srow = s + (size_t)b * L_;

    const float v1 = srow[n];
    const float v2 = (n < L_ - 512) ? srow[512 + n] : -1e30f;
    float lmax = fmaxf(v1, v2);
    for (int off = 32; off > 0; off >>= 1) lmax = fmaxf(lmax, __shfl_xor(lmax, off));
    if ((n & 63) == 0) red[n >> 6] = lmax;
    __syncthreads();
    float gmax = red[0];
    #pragma unroll
    for (int i = 1; i < 8; ++i) gmax = fmaxf(gmax, red[i]);
    __syncthreads();
    float lsum = expf(v1 - gmax) + ((n < L_ - 512) ? expf(v2 - gmax) : 0.f);
    for (int off = 32; off > 0; off >>= 1) lsum += __shfl_xor(lsum, off);
    if ((n & 63) == 0) red[n >> 6] = lsum;
    __syncthreads();
    float gsum = 0.f;
    #pragma unroll
    for (int i = 0; i < 8; ++i) gsum += red[i];
    const float inv = 1.f / gsum;

    const int l0 = c * CRL;
    if (n < CRL) ash[n] = expf(srow[l0 + n] - gmax) * inv;
    __syncthreads();

    const float* xb = x + ((size_t)b * L_ + l0) * N_;
    float acc = 0.f;
    #pragma unroll 3
    for (int l = 0; l < CRL; l++) acc += ash[l] * xb[(size_t)l * N_ + n];
    craw_p[(size_t)(b * CRCH + c) * N_ + n] = acc;
}

__device__ __forceinline__ float gelu_exact(float v) {
    return 0.5f * v * (1.0f + erff(v * 0.70710678118654752440f));
}

// ---------------------------------------------------------------------------
// Kernel 5: reduce partials + center MLP -> center. grid B_, 512 thr.
// ---------------------------------------------------------------------------
__global__ __launch_bounds__(512) void center_mlp_kernel(
    const float* __restrict__ craw_p,
    const float* __restrict__ Wc1, const float* __restrict__ bc1,
    const float* __restrict__ Wc2, const float* __restrict__ bc2,
    const float* __restrict__ Wcn, const float* __restrict__ bcn,
    float* __restrict__ center)
{
    const int b = blockIdx.x;
    const int t = threadIdx.x;
    const int col = t & 63;
    const int seg = t >> 6;
    __shared__ float cr[N_];
    __shared__ float psum[8][D_];
    __shared__ float h1[D_];
    __shared__ float h2[D_];

    {
        float acc = 0.f;
        #pragma unroll
        for (int c = 0; c < CRCH; ++c) acc += craw_p[(size_t)(b * CRCH + c) * N_ + t];
        cr[t] = acc;
    }
    __syncthreads();
    {
        float p = 0.f;
        #pragma unroll 8
        for (int m = seg * 64; m < seg * 64 + 64; ++m) p += cr[m] * Wc1[m * D_ + col];
        psum[seg][col] = p;
    }
    __syncthreads();
    if (t < D_) {
        float acc = bc1[t];
        #pragma unroll
        for (int s2 = 0; s2 < 8; ++s2) acc += psum[s2][t];
        h1[t] = gelu_exact(acc);
    }
    __syncthreads();
    if (t < D_) {
        float acc = bc2[t];
        #pragma unroll 8
        for (int j = 0; j < D_; j++) acc += h1[j] * Wc2[j * D_ + t];
        h2[t] = gelu_exact(acc);
    }
    __syncthreads();
    {
        float acc = bcn[t];
        #pragma unroll 8
        for (int j = 0; j < D_; j++) acc += h2[j] * Wcn[j * N_ + t];
        center[b * N_ + t] = acc;
    }
}

// ---------------------------------------------------------------------------
// Kernel 6: cg[b,n] = center[b]·Wg[512+.,n] + bg[n].
// ---------------------------------------------------------------------------
__global__ __launch_bounds__(512) void cg_kernel(
    const float* __restrict__ center, const float* __restrict__ Wg,
    const float* __restrict__ bg, float* __restrict__ cg)
{
    const int nc = blockIdx.x;
    const int b  = blockIdx.y;
    const int t  = threadIdx.x;
    const int col = nc * 64 + (t & 63);
    const int seg = t >> 6;
    __shared__ float cs[N_];
    __shared__ float psum[8][64];

    cs[t] = center[b * N_ + t];
    __syncthreads();
    {
        float p = 0.f;
        const float* wp = Wg + (size_t)(N_ + seg * 64) * N_ + col;
        #pragma unroll 8
        for (int m = 0; m < 64; ++m) { p += cs[seg * 64 + m] * wp[0]; wp += N_; }
        psum[seg][t & 63] = p;
    }
    __syncthreads();
    if (t < 64) {
        float acc = bg[nc * 64 + t];
        #pragma unroll
        for (int s2 = 0; s2 < 8; ++s2) acc += psum[s2][t];
        cg[b * N_ + nc * 64 + t] = acc;
    }
}

// ---------------------------------------------------------------------------
// Kernel 7 (MEGA v2): gate GEMM + fuse + out GEMM + residual + LayerNorm.
// One 64x512 tile per block; 256 threads = 4 waves; wave wv owns cols
// wv*128..+127 and ALL 64 rows (acc[2][4]).  A (ring, 64x512 bf16) staged
// once in 64 KB LDS; B staged per K-step (BK=64, 512x64 bf16 = 64 KB) via
// global_load_lds with the m97 2-barrier pattern.  Gate epilogue rewrites
// A in place (ring -> fused); LN scratch reuses dead LDS.
// ---------------------------------------------------------------------------
#define MKLOOP(BTP)                                                            \
    for (int step = 0; step < 8; ++step) {                                     \
        const int k0 = step * 64;                                              \
        __syncthreads();                                                       \
        _Pragma("unroll")                                                      \
        for (int i = 0; i < 16; ++i) {                                         \
            const int nrow = i * 32 + wv * 8;                                  \
            async_cp16(BTP + (size_t)(nrow + rln) * N_ + k0 +                  \
                           (((lane & 7) ^ rln) << 3),                          \
                       Bsh + nrow * 64);                                       \
        }                                                                      \
        __syncthreads();                                                       \
        _Pragma("unroll")                                                      \
        for (int ks = 0; ks < 4; ++ks) {                                       \
            const int jA = step * 8 + ks * 2 + half;                           \
            const int jB = ks * 2 + half;                                      \
            const int ar0 = m32, ar1 = 32 + m32;                               \
            bf16x8 a0 = *(const bf16x8*)(Ash + ar0 * 512 + ((jA ^ (ar0 & 7)) << 3)); \
            bf16x8 a1 = *(const bf16x8*)(Ash + ar1 * 512 + ((jA ^ (ar1 & 7)) << 3)); \
            _Pragma("unroll")                                                  \
            for (int ni = 0; ni < 4; ++ni) {                                   \
                const int n = wv * 128 + ni * 32 + m32;                        \
                bf16x8 b = *(const bf16x8*)(Bsh + n * 64 + ((jB ^ (n & 7)) << 3)); \
                acc[0][ni] = __builtin_amdgcn_mfma_f32_32x32x16_bf16(a0, b, acc[0][ni], 0, 0, 0); \
                acc[1][ni] = __builtin_amdgcn_mfma_f32_32x32x16_bf16(a1, b, acc[1][ni], 0, 0, 0); \
            }                                                                  \
        }                                                                      \
    }

__global__ __launch_bounds__(256, 1) void mega_kernel(
    const __hip_bfloat16* __restrict__ ring,
    const __hip_bfloat16* __restrict__ WgT,
    const __hip_bfloat16* __restrict__ WfT,
    const float* __restrict__ cg, const float* __restrict__ center,
    const float* __restrict__ x, const float* __restrict__ bfv,
    const float* __restrict__ gamma, const float* __restrict__ beta,
    float* __restrict__ out)
{
    __shared__ __hip_bfloat16 Ash[MT * 512];   // 64 KB, swizzled, whole K
    __shared__ __hip_bfloat16 Bsh[512 * 64];   // 64 KB, one BK=64 step
    const int tid  = threadIdx.x;
    const int lane = tid & 63;
    const int wv   = tid >> 6;     // 0..3 = column group
    const int m32  = lane & 31;
    const int half = lane >> 5;
    const int rln  = lane >> 3;    // 0..7
    const int row0 = blockIdx.x * MT;

    // stage ring rows once: wave wv stages rows wv*16..+15 (1 row / instr)
    #pragma unroll
    for (int r8 = 0; r8 < 16; ++r8) {
        const int r = wv * 16 + r8;
        async_cp16(ring + (size_t)(row0 + r) * N_ + ((lane ^ (r & 7)) << 3),
                   Ash + r * 512);
    }

    f32x16 acc[2][4];
    #pragma unroll
    for (int rg = 0; rg < 2; ++rg)
        #pragma unroll
        for (int ni = 0; ni < 4; ++ni)
            #pragma unroll
            for (int e = 0; e < 16; ++e) acc[rg][ni][e] = 0.f;

    // ---- gate GEMM: ring @ WgT^T ----
    MKLOOP(WgT)
    __syncthreads();   // all A-frag reads done before in-place rewrite

    // ---- gate epilogue: fused = g*ring + (1-g)*center, in place in Ash ----
    #pragma unroll
    for (int rg = 0; rg < 2; ++rg)
        #pragma unroll
        for (int ni = 0; ni < 4; ++ni) {
            const int col = wv * 128 + ni * 32 + m32;
            #pragma unroll
            for (int reg = 0; reg < 16; ++reg) {
                const int rl = rg * 32 + (reg & 3) + 8 * (reg >> 2) + 4 * half;
                const int rgl = row0 + rl;
                const int b  = rgl / L_;
                const float logit = acc[rg][ni][reg] + cg[b * N_ + col];
                const float g = 1.f / (1.f + expf(-logit));
                const int ix = sw_idx(rl, col);
                const float rv = __bfloat162float(Ash[ix]);
                const float f = g * rv + (1.f - g) * center[b * N_ + col];
                Ash[ix] = __float2bfloat16(f);
            }
        }

    #pragma unroll
    for (int rg = 0; rg < 2; ++rg)
        #pragma unroll
        for (int ni = 0; ni < 4; ++ni)
            #pragma unroll
            for (int e = 0; e < 16; ++e) acc[rg][ni][e] = 0.f;

    // ---- out GEMM: fused @ WfT^T  (leading barrier orders epilogue writes)
    MKLOOP(WfT)

    // ---- h = acc + bf + x ----
    #pragma unroll
    for (int rg = 0; rg < 2; ++rg)
        #pragma unroll
        for (int ni = 0; ni < 4; ++ni) {
            const int col = wv * 128 + ni * 32 + m32;
            const float bfc = bfv[col];
            #pragma unroll
            for (int reg = 0; reg < 16; ++reg) {
                const int rl = rg * 32 + (reg & 3) + 8 * (reg >> 2) + 4 * half;
                acc[rg][ni][reg] += bfc + x[(size_t)(row0 + rl) * N_ + col];
            }
        }
    __syncthreads();   // LDS now dead -> reuse as LN scratch

    float* rsum = (float*)Ash;          // [4][64]
    float* rsq  = (float*)Ash + 256;    // [4][64]
    float* muv  = (float*)Ash + 512;    // [64][2]

    // per-row partials over this wave's 128 cols
    #pragma unroll
    for (int rg = 0; rg < 2; ++rg)
        #pragma unroll
        for (int reg = 0; reg < 16; ++reg) {
            float sv = acc[rg][0][reg] + acc[rg][1][reg] + acc[rg][2][reg] + acc[rg][3][reg];
            float qv = acc[rg][0][reg] * acc[rg][0][reg] + acc[rg][1][reg] * acc[rg][1][reg]
                     + acc[rg][2][reg] * acc[rg][2][reg] + acc[rg][3][reg] * acc[rg][3][reg];
            #pragma unroll
            for (int off = 16; off > 0; off >>= 1) {
                sv += __shfl_xor(sv, off);
                qv += __shfl_xor(qv, off);
            }
            if (m32 == 0) {
                const int rl = rg * 32 + (reg & 3) + 8 * (reg >> 2) + 4 * half;
                rsum[wv * 64 + rl] = sv;
                rsq [wv * 64 + rl] = qv;
            }
        }
    __syncthreads();
    if (tid < 64) {
        const float S = rsum[tid] + rsum[64 + tid] + rsum[128 + tid] + rsum[192 + tid];
        const float Q = rsq[tid]  + rsq[64 + tid]  + rsq[128 + tid]  + rsq[192 + tid];
        const float mu  = S * (1.0f / N_);
        const float var = Q * (1.0f / N_) - mu * mu;
        muv[tid * 2]     = mu;
        muv[tid * 2 + 1] = 1.0f / sqrtf(var + 1e-5f);
    }
    __syncthreads();

    // normalize + store
    #pragma unroll
    for (int rg = 0; rg < 2; ++rg)
        #pragma unroll
        for (int ni = 0; ni < 4; ++ni) {
            const int col = wv * 128 + ni * 32 + m32;
            const float gm = gamma[col];
            const float bt = beta[col];
            #pragma unroll
            for (int reg = 0; reg < 16; ++reg) {
                const int rl = rg * 32 + (reg & 3) + 8 * (reg >> 2) + 4 * half;
                out[(size_t)(row0 + rl) * N_ + col] =
                    (acc[rg][ni][reg] - muv[rl * 2]) * muv[rl * 2 + 1] * gm + bt;
            }
        }
}

// ---------------------------------------------------------------------------
extern "C" void kernel_launch(void* const* d_in, const int* in_sizes, int n_in,
                              void* d_out, int out_size, void* d_ws, size_t ws_size,
                              hipStream_t stream) {
    const float* x       = (const float*)d_in[0];
    const float* ve      = (const float*)d_in[1];
    const float* Wq      = (const float*)d_in[2];
    const float* bq      = (const float*)d_in[3];
    const float* Wk      = (const float*)d_in[4];
    const float* bk      = (const float*)d_in[5];
    const float* Wscore  = (const float*)d_in[6];
    const float* bscore  = (const float*)d_in[7];
    const float* Wc1     = (const float*)d_in[8];
    const float* bc1     = (const float*)d_in[9];
    const float* Wc2     = (const float*)d_in[10];
    const float* bc2     = (const float*)d_in[11];
    const float* Wcn     = (const float*)d_in[12];
    const float* bcn     = (const float*)d_in[13];
    const float* Wg      = (const float*)d_in[14];
    const float* bg      = (const float*)d_in[15];
    const float* Wf      = (const float*)d_in[16];
    const float* bf      = (const float*)d_in[17];
    const float* gamma   = (const float*)d_in[18];
    const float* beta    = (const float*)d_in[19];
    float* out = (float*)d_out;

    char* p = (char*)d_ws;
    float* ws_w    = (float*)p; p += N_ * TOPK_ * sizeof(float);
    int*   ws_idx  = (int*)p;   p += N_ * TOPK_ * sizeof(int);
    float* ws_s    = (float*)p; p += B_ * L_ * sizeof(float);
    float* ws_crp  = (float*)p; p += B_ * CRCH * N_ * sizeof(float);
    float* ws_cent = (float*)p; p += B_ * N_ * sizeof(float);
    float* ws_cg   = (float*)p; p += B_ * N_ * sizeof(float);
    float* ws_Q    = (float*)p; p += N_ * H_ * sizeof(float);
    float* ws_K    = (float*)p; p += N_ * H_ * sizeof(float);
    __hip_bfloat16* ws_ring = (__hip_bfloat16*)p; p += (size_t)M_ * N_ * sizeof(__hip_bfloat16);
    __hip_bfloat16* ws_WgT  = (__hip_bfloat16*)p; p += (size_t)N_ * N_ * sizeof(__hip_bfloat16);
    __hip_bfloat16* ws_WfT  = (__hip_bfloat16*)p; p += (size_t)N_ * N_ * sizeof(__hip_bfloat16);

    prep_kernel<<<1056, 256, 0, stream>>>(Wg, Wf, ws_WgT, ws_WfT,
                                          ve, Wq, bq, Wk, bk, ws_Q, ws_K);
    topk_kernel<<<N_, 64, 0, stream>>>(ws_Q, ws_K, ws_w, ws_idx);
    ring_kernel<<<M_ / RPB, 512, 0, stream>>>(x, ws_w, ws_idx, Wscore, bscore,
                                              ws_ring, ws_s);
    center_raw_kernel<<<B_ * CRCH, 512, 0, stream>>>(x, ws_s, ws_crp);
    center_mlp_kernel<<<B_, 512, 0, stream>>>(ws_crp, Wc1, bc1, Wc2, bc2,
                                              Wcn, bcn, ws_cent);
    cg_kernel<<<dim3(8, B_), 512, 0, stream>>>(ws_cent, Wg, bg, ws_cg);
    mega_kernel<<<M_ / MT, 256, 0, stream>>>(ws_ring, ws_WgT, ws_WfT,
                                             ws_cg, ws_cent, x, bf,
                                             gamma, beta, out);
}